// Round 7
// baseline (43262.671 us; speedup 1.0000x reference)
//
#include <hip/hip_runtime.h>
#include <cmath>

// ---------------------------------------------------------------------------
// GridGRU on MI355X. Round 7: cached exchange + per-barrier acquire fence.
// Writers: sc0+sc1 write-through stores (coherence point, L2 never dirty).
// Readers: ONE agent-acquire fence (buffer_inv) per barrier, then plain
// cached loads. Flags stay uncached. Numerics identical to rounds 5/6.
// N=32, T=512, D=H=1024. weight (2048,6144) row-major f32, bias 6144.
// ---------------------------------------------------------------------------

#define LDW 6144
typedef float  f32x4 __attribute__((ext_vector_type(4)));
typedef short  s16x8 __attribute__((ext_vector_type(8)));

__device__ __forceinline__ float sigf(float v){ return 1.f/(1.f+__expf(-v)); }
__device__ __forceinline__ unsigned short f2b(float f){
    unsigned u = __float_as_uint(f);
    return (unsigned short)((u + 0x7FFFu + ((u>>16)&1u)) >> 16);
}

// ---- system-coherent (cache-bypass) store/load helpers --------------------
__device__ __forceinline__ void st_sc1(float* p, float v){
    asm volatile("global_store_dword %0, %1, off sc0 sc1"
                 :: "v"(p), "v"(v) : "memory");
}
__device__ __forceinline__ void st_sc4(float* p, f32x4 v){
    asm volatile("global_store_dwordx4 %0, %1, off sc0 sc1"
                 :: "v"(p), "v"(v) : "memory");
}
__device__ __forceinline__ void st_sc_b16(unsigned short* p, unsigned v){
    asm volatile("global_store_short %0, %1, off sc0 sc1"
                 :: "v"(p), "v"(v) : "memory");
}
__device__ __forceinline__ void st_sc_u32(unsigned* p, unsigned v){
    asm volatile("global_store_dword %0, %1, off sc0 sc1"
                 :: "v"(p), "v"(v) : "memory");
}
__device__ __forceinline__ unsigned ld_sc_u32(const unsigned* p){
    unsigned v;
    asm volatile("global_load_dword %0, %1, off sc0 sc1\n\t"
                 "s_waitcnt vmcnt(0)"
                 : "=v"(v) : "v"(p) : "memory");
    return v;
}

// ---- WT[j][k] = bf16(weight[k][j]); j<6144, k<2048 -------------------------
__global__ __launch_bounds__(256)
void k_wt(const float* __restrict__ w, unsigned short* __restrict__ wt)
{
    __shared__ float t[64][65];
    const int j0 = blockIdx.x*64, k0 = blockIdx.y*64;
    for (int i = threadIdx.x; i < 4096; i += 256) {
        int r = i>>6, c = i&63;
        t[r][c] = w[(size_t)(k0+r)*LDW + j0 + c];
    }
    __syncthreads();
    for (int i = threadIdx.x; i < 4096; i += 256) {
        int jr = i>>6, kc = i&63;
        wt[(size_t)(j0+jr)*2048 + k0 + kc] = f2b(t[kc][jr]);
    }
}

// ---- WhT[j][k] = weight[1024+k][j] f32; j<3072, k<1024 ---------------------
__global__ __launch_bounds__(256)
void k_wht(const float* __restrict__ w, float* __restrict__ wht)
{
    __shared__ float t[64][65];
    const int j0 = blockIdx.x*64, k0 = blockIdx.y*64;
    for (int i = threadIdx.x; i < 4096; i += 256) {
        int r = i>>6, c = i&63;
        t[r][c] = w[(size_t)(1024+k0+r)*LDW + j0 + c];
    }
    __syncthreads();
    for (int i = threadIdx.x; i < 4096; i += 256) {
        int jr = i>>6, kc = i&63;
        wht[(size_t)(j0+jr)*1024 + k0 + kc] = t[kc][jr];
    }
}

// ---- x (f32) -> bf16 -------------------------------------------------------
__global__ __launch_bounds__(256)
void k_xbf(const float* __restrict__ x, unsigned short* __restrict__ o)
{
    long i = ((long)blockIdx.x*256 + threadIdx.x)*4;
    float4 v = *(const float4*)&x[i];
    ushort4 r = { f2b(v.x), f2b(v.y), f2b(v.z), f2b(v.w) };
    *(ushort4*)&o[i] = r;
}

// ---------------------------------------------------------------------------
// bf16 MFMA GEMM (unchanged; validated rounds 3-6).
// ---------------------------------------------------------------------------
template<int AMODE, int EMODE>
__global__ __launch_bounds__(256)
void gemm_mfma(const unsigned short* __restrict__ A1,
               const unsigned short* __restrict__ A2,
               const unsigned short* __restrict__ Bw,
               float* __restrict__ C, int ldc,
               const float* __restrict__ bias,
               const float* __restrict__ X,
               float* __restrict__ UD,
               unsigned short* __restrict__ RX,
               int K, int t0)
{
    __shared__ unsigned short Als[128*32];
    __shared__ unsigned short Bls[128*32];
    const int tid = threadIdx.x;
    const int m_base = blockIdx.y*128;
    const int n_base = blockIdx.x*128;
    const int row0 = tid>>2, row1 = row0+64, quad = tid&3;
    const int wv = tid>>6, lane = tid&63;
    const int wr = (wv>>1)*64, wc = (wv&1)*64;
    const int l15 = lane&15, l4 = lane>>4;

    f32x4 acc[4][4] = {};

    for (int k0 = 0; k0 < K; k0 += 32) {
        const int kq = k0 + quad*8;
        s16x8 a0, a1, b0, b1;
        {
            long r0 = m_base + row0, r1 = m_base + row1;
            const unsigned short *p0, *p1;
            if (AMODE == 1) {
                long g0 = (r0>>6)*512 + t0 + (r0&63);
                long g1 = (r1>>6)*512 + t0 + (r1&63);
                p0 = A1 + g0*1024 + kq; p1 = A1 + g1*1024 + kq;
            } else if (AMODE == 2 && k0 >= 1024) {
                p0 = A2 + r0*1024 + (kq-1024); p1 = A2 + r1*1024 + (kq-1024);
            } else {
                p0 = A1 + r0*1024 + kq; p1 = A1 + r1*1024 + kq;
            }
            a0 = *(const s16x8*)p0; a1 = *(const s16x8*)p1;
        }
        b0 = *(const s16x8*)(Bw + (size_t)(n_base+row0)*2048 + kq);
        b1 = *(const s16x8*)(Bw + (size_t)(n_base+row1)*2048 + kq);
        __syncthreads();
        *(s16x8*)&Als[row0*32 + quad*8] = a0;
        *(s16x8*)&Als[row1*32 + quad*8] = a1;
        *(s16x8*)&Bls[row0*32 + quad*8] = b0;
        *(s16x8*)&Bls[row1*32 + quad*8] = b1;
        __syncthreads();
        s16x8 af[4], bfr[4];
#pragma unroll
        for (int i = 0; i < 4; ++i) {
            af[i]  = *(const s16x8*)&Als[(wr + i*16 + l15)*32 + l4*8];
            bfr[i] = *(const s16x8*)&Bls[(wc + i*16 + l15)*32 + l4*8];
        }
#pragma unroll
        for (int mi = 0; mi < 4; ++mi)
#pragma unroll
            for (int ni = 0; ni < 4; ++ni)
                acc[mi][ni] = __builtin_amdgcn_mfma_f32_16x16x32_bf16(
                    af[mi], bfr[ni], acc[mi][ni], 0, 0, 0);
    }

#pragma unroll
    for (int mi = 0; mi < 4; ++mi)
#pragma unroll
    for (int ni = 0; ni < 4; ++ni)
#pragma unroll
    for (int q = 0; q < 4; ++q) {
        int row = m_base + wr + mi*16 + l4*4 + q;
        int col = n_base + wc + ni*16 + l15;
        float v = acc[mi][ni][q] + bias[col];
        if (EMODE == 0) {
            C[(size_t)row*ldc + col] = v;
        } else if (EMODE == 1) {
            float s = sigf(v);
            if (col < 1024) {
                UD[(size_t)row*1024 + col] = s;
            } else {
                int jj = col - 1024;
                RX[(size_t)row*1024 + jj] = f2b(s * X[(size_t)row*1024 + jj]);
            }
        } else {
            float hc = tanhf(v);
            float xv = X[(size_t)row*1024 + col];
            float ud = UD[(size_t)row*1024 + col];
            C[(size_t)row*1024 + col] = xv + ud*(hc - xv);
        }
    }
}

// ---------------------------------------------------------------------------
// Flag-array grid barrier + agent acquire fence.
// Arrival: sc store to own flag line (syncthreads drained vmcnt first).
// Wait: threads 0..255 poll one peer flag each (relaxed uncached).
// Then ONE buffer_inv (acquire fence) -> subsequent plain loads are fresh.
// ---------------------------------------------------------------------------
__device__ __forceinline__ void flagbar(unsigned* flags, unsigned& bidx)
{
    __syncthreads();                 // all waves' sc data-stores drained
    ++bidx;
    const int tid = threadIdx.x;
    if (tid == 0) st_sc_u32(&flags[(unsigned)blockIdx.x * 32], bidx);
    if (tid < 256) {
        const unsigned* f = &flags[(unsigned)tid * 32];
        while (ld_sc_u32(f) < bidx) __builtin_amdgcn_s_sleep(1);
    }
    __syncthreads();
    __builtin_amdgcn_fence(__ATOMIC_ACQUIRE, "agent");   // inv L1/L2 once
}

// ---------------------------------------------------------------------------
// Persistent scan: 64 steps/launch, 2 barriers/step, 129 barriers/launch.
// 256 blocks x 512 threads, 1 block/CU. LDS tile padded [32][1028].
// Global stores: sc1 write-through only (L2 never dirty -> inv-safe).
// Global loads: plain cached (fresh after the barrier fence).
// ---------------------------------------------------------------------------
__global__ __launch_bounds__(512)
void scan_coop(const float* __restrict__ gates_c,
               const float* __restrict__ WhT,
               const float* __restrict__ prev_ht,
               float* __restrict__ hping,            // [2][32768]
               float* __restrict__ u_buf,
               float* __restrict__ rh_buf,
               unsigned short* __restrict__ htbf,    // [32][512][1024] bf16
               unsigned* __restrict__ flags,
               int t0, int bidx0)
{
    __shared__ float sh[32*1028];
    __shared__ float red[512];
    const int tid = threadIdx.x;
    const int bid = blockIdx.x;
    unsigned bidx = (unsigned)bidx0;

    if (t0 == 0) {
        long g = (long)bid*512 + tid;
        if (g < 8192) {
            f32x4 v = *(const f32x4*)&prev_ht[g*4];
            st_sc4(&hping[g*4], v);
        }
    }
    flagbar(flags, bidx);     // unconditional: 129 barriers per launch

    for (int tl = 0; tl < 64; ++tl) {
        const int t = t0 + tl;
        const float* hin  = hping + (size_t)(t&1)*32768;
        float*       hout = hping + (size_t)((t+1)&1)*32768;

        // ---- stage h (plain cached loads) -------------------------------
        for (int i = tid*4; i < 32768; i += 2048) {
            int n = i >> 10, k = i & 1023;
            *(f32x4*)&sh[n*1028 + k] = *(const f32x4*)&hin[i];
        }
        __syncthreads();

        // ---------------- phase A: ur = sig(g + h @ Whtg) ----------------
        {
            const int j  = bid*8 + (tid&7);       // 0..2047
            const int n  = (tid>>3) & 31;
            const int kh = tid>>8;                // split-K 2
            const float* wrow = WhT + (size_t)j*1024 + kh*512;
            const float* hrow = sh + n*1028 + kh*512;
            float acc = 0.f;
#pragma unroll 8
            for (int k = 0; k < 512; k += 4) {
                float4 wv = *(const float4*)&wrow[k];
                float4 hv = *(const float4*)&hrow[k];
                acc = fmaf(hv.x, wv.x, acc);
                acc = fmaf(hv.y, wv.y, acc);
                acc = fmaf(hv.z, wv.z, acc);
                acc = fmaf(hv.w, wv.w, acc);
            }
            if (kh) red[tid & 255] = acc;
            __syncthreads();
            if (!kh) {
                acc += red[tid];
                float g = gates_c[(size_t)(n*64 + tl)*3072 + j];
                float s = sigf(g + acc);
                if (j < 1024) st_sc1(&u_buf[n*1024 + j], s);
                else st_sc1(&rh_buf[n*1024 + (j-1024)], s * sh[n*1028 + (j-1024)]);
            }
        }
        flagbar(flags, bidx);

        // ---- stage rh (plain cached loads) ------------------------------
        for (int i = tid*4; i < 32768; i += 2048) {
            int n = i >> 10, k = i & 1023;
            *(f32x4*)&sh[n*1028 + k] = *(const f32x4*)&rh_buf[i];
        }
        __syncthreads();

        // -------- phase B: hc = tanh(g2 + rh @ Wsm); h' = h + u(hc-h) -----
        {
            const int jb = bid*4 + (tid&3);       // 0..1023
            const int nb = (tid>>2) & 31;
            const int kq = tid>>7;                // split-K 4
            float h0 = hin[nb*1024 + jb];         // plain cached
            float uu = u_buf[nb*1024 + jb];       // plain cached
            const float* wrow = WhT + (size_t)(2048 + jb)*1024 + kq*256;
            const float* rrow = sh + nb*1028 + kq*256;
            float acc = 0.f;
#pragma unroll 8
            for (int k = 0; k < 256; k += 4) {
                float4 wv = *(const float4*)&wrow[k];
                float4 rv = *(const float4*)&rrow[k];
                acc = fmaf(rv.x, wv.x, acc);
                acc = fmaf(rv.y, wv.y, acc);
                acc = fmaf(rv.z, wv.z, acc);
                acc = fmaf(rv.w, wv.w, acc);
            }
            if (kq) red[(kq-1)*128 + (tid&127)] = acc;
            __syncthreads();
            if (!kq) {
                acc += red[tid] + red[128+tid] + red[256+tid];
                float g  = gates_c[(size_t)(nb*64 + tl)*3072 + 2048 + jb];
                float hc = tanhf(g + acc);
                float hn = h0 + uu*(hc - h0);
                st_sc1(&hout[nb*1024 + jb], hn);
                st_sc_b16(&htbf[((size_t)nb*512 + t)*1024 + jb], (unsigned)f2b(hn));
            }
        }
        flagbar(flags, bidx);
    }
}

__global__ __launch_bounds__(256)
void k_lasth(const float* __restrict__ hping, float* __restrict__ dst)
{
    int i = blockIdx.x*256 + threadIdx.x;     // 32768
    dst[i] = hping[i];
}

// ---------------------------------------------------------------------------
extern "C" void kernel_launch(void* const* d_in, const int* in_sizes, int n_in,
                              void* d_out, int out_size, void* d_ws, size_t ws_size,
                              hipStream_t stream)
{
    const float* x       = (const float*)d_in[0];
    const float* prev_ht = (const float*)d_in[1];
    const float* weight  = (const float*)d_in[2];
    const float* bias    = (const float*)d_in[3];
    float* out = (float*)d_out;
    float* ws  = (float*)d_ws;

    // ws layout (float units):
    unsigned short* WT   = (unsigned short*)ws;                // 6,291,456 f
    float* WhT           = ws + 6291456;                       // 3,145,728 f
    float* chunk         = ws + 9437184;                       // 6,291,456 f
    unsigned short* htbf = (unsigned short*)(ws + 15728640);   // 8,388,608 f
    unsigned short* xbf  = (unsigned short*)(ws + 24117248);   // 8,388,608 f
    float* hping         = ws + 32505856;                      // 65,536 f
    float* u_buf         = ws + 32571392;                      // 32,768 f
    float* rh_buf        = ws + 32604160;                      // 32,768 f
    unsigned* flags      = (unsigned*)(ws + 32636928);         // 8,192 u32 (32 KB)
    unsigned short* rxbf = (unsigned short*)(ws + 6291456);    // overlays WhT+chunk
    const size_t needed = (size_t)(32636928 + 8192) * 4;       // 130.6 MB
    if (ws_size < needed) return;

    hipMemsetAsync(flags, 0, 32768, stream);
    k_wt <<<dim3(96,32), 256, 0, stream>>>(weight, WT);
    k_wht<<<dim3(48,16), 256, 0, stream>>>(weight, WhT);
    k_xbf<<<16384, 256, 0, stream>>>(x, xbf);

    for (int seg = 0; seg < 8; ++seg) {
        int t0 = seg * 64;
        int bidx0 = seg * 129;
        gemm_mfma<1,0><<<dim3(24,16), 256, 0, stream>>>(
            xbf, nullptr, WT, chunk, 3072, bias, nullptr, nullptr, nullptr,
            1024, t0);
        const float* gc = chunk;
        void* args[] = { (void*)&gc, (void*)&WhT, (void*)&prev_ht,
                         (void*)&hping, (void*)&u_buf, (void*)&rh_buf,
                         (void*)&htbf, (void*)&flags, (void*)&t0, (void*)&bidx0 };
        hipLaunchCooperativeKernel((void*)scan_coop, dim3(256), dim3(512),
                                   args, 0, stream);
    }

    // depth urd: [x|ht] @ W[:,3072:5120] -> sig -> ud (d_out), rx (bf16)
    gemm_mfma<2,1><<<dim3(16,128), 256, 0, stream>>>(
        xbf, htbf, WT + (size_t)3072*2048, nullptr, 0, bias + 3072,
        x, out, rxbf, 2048, 0);
    // depth hc: [rx|ht] @ W[:,5120:6144] -> tanh -> final out
    gemm_mfma<2,2><<<dim3(8,128), 256, 0, stream>>>(
        rxbf, htbf, WT + (size_t)5120*2048, out, 1024, bias + 5120,
        x, out, nullptr, 2048, 0);

    k_lasth<<<128, 256, 0, stream>>>(hping, out + (size_t)16384*1024);
}

// Round 9
// 19316.351 us; speedup vs baseline: 2.2397x; 2.2397x over previous
//
#include <hip/hip_runtime.h>
#include <cmath>

// ---------------------------------------------------------------------------
// GridGRU on MI355X. Round 9: f32 recurrent state + split-bf16 (hi/lo) MFMA
// scan. 32-block flag-barrier persistent scan, virgin-ring cached exchange.
// N=32, T=512, D=H=1024. weight (2048,6144) row-major f32, bias 6144.
// ---------------------------------------------------------------------------

#define LDW 6144
#define CT 32                      // timesteps per segment (16 segments)
typedef float  f32x4 __attribute__((ext_vector_type(4)));
typedef short  s16x8 __attribute__((ext_vector_type(8)));

__device__ __forceinline__ float sigf(float v){ return 1.f/(1.f+__expf(-v)); }
__device__ __forceinline__ unsigned short f2b(float f){
    unsigned u = __float_as_uint(f);
    return (unsigned short)((u + 0x7FFFu + ((u>>16)&1u)) >> 16);
}
__device__ __forceinline__ float b2f(unsigned short u){
    return __uint_as_float(((unsigned)u) << 16);
}

// ---- system-coherent write-through / uncached helpers ---------------------
__device__ __forceinline__ void st_sc1(float* p, float v){
    asm volatile("global_store_dword %0, %1, off sc0 sc1"
                 :: "v"(p), "v"(v) : "memory");
}
__device__ __forceinline__ void st_sc_b16(unsigned short* p, unsigned v){
    asm volatile("global_store_short %0, %1, off sc0 sc1"
                 :: "v"(p), "v"(v) : "memory");
}
__device__ __forceinline__ void st_sc_u32(unsigned* p, unsigned v){
    asm volatile("global_store_dword %0, %1, off sc0 sc1"
                 :: "v"(p), "v"(v) : "memory");
}
__device__ __forceinline__ unsigned ld_sc_u32(const unsigned* p){
    unsigned v;
    asm volatile("global_load_dword %0, %1, off sc0 sc1\n\t"
                 "s_waitcnt vmcnt(0)"
                 : "=v"(v) : "v"(p) : "memory");
    return v;
}

// ---- WT[j][k] = bf16(weight[k][j]); j<6144, k<2048 -------------------------
__global__ __launch_bounds__(256)
void k_wt(const float* __restrict__ w, unsigned short* __restrict__ wt)
{
    __shared__ float t[64][65];
    const int j0 = blockIdx.x*64, k0 = blockIdx.y*64;
    for (int i = threadIdx.x; i < 4096; i += 256) {
        int r = i>>6, c = i&63;
        t[r][c] = w[(size_t)(k0+r)*LDW + j0 + c];
    }
    __syncthreads();
    for (int i = threadIdx.x; i < 4096; i += 256) {
        int jr = i>>6, kc = i&63;
        wt[(size_t)(j0+jr)*2048 + k0 + kc] = f2b(t[kc][jr]);
    }
}

// ---- Wlo[j][k] = bf16-residual of weight[1024+k][j]; j<3072, k<1024 --------
__global__ __launch_bounds__(256)
void k_wlo(const float* __restrict__ w, unsigned short* __restrict__ wlo)
{
    __shared__ float t[64][65];
    const int j0 = blockIdx.x*64, k0 = blockIdx.y*64;
    for (int i = threadIdx.x; i < 4096; i += 256) {
        int r = i>>6, c = i&63;
        t[r][c] = w[(size_t)(1024+k0+r)*LDW + j0 + c];
    }
    __syncthreads();
    for (int i = threadIdx.x; i < 4096; i += 256) {
        int jr = i>>6, kc = i&63;
        float v = t[kc][jr];
        unsigned short hi = f2b(v);
        wlo[(size_t)(j0+jr)*1024 + k0 + kc] = f2b(v - b2f(hi));
    }
}

// ---- x (f32) -> bf16 -------------------------------------------------------
__global__ __launch_bounds__(256)
void k_xbf(const float* __restrict__ x, unsigned short* __restrict__ o)
{
    long i = ((long)blockIdx.x*256 + threadIdx.x)*4;
    float4 v = *(const float4*)&x[i];
    ushort4 r = { f2b(v.x), f2b(v.y), f2b(v.z), f2b(v.w) };
    *(ushort4*)&o[i] = r;
}

// ---------------------------------------------------------------------------
// bf16 MFMA GEMM (structure validated rounds 3-7).
// AMODE 1 (gates, CT=32): row r -> x row (r>>5)*512 + t0 + (r&31).
// AMODE 2 concat-K: k>=1024 -> A2 = htR t-major: ((r&511)*32 + (r>>9))*1024.
// ---------------------------------------------------------------------------
template<int AMODE, int EMODE>
__global__ __launch_bounds__(256)
void gemm_mfma(const unsigned short* __restrict__ A1,
               const unsigned short* __restrict__ A2,
               const unsigned short* __restrict__ Bw,
               float* __restrict__ C, int ldc,
               const float* __restrict__ bias,
               const float* __restrict__ X,
               float* __restrict__ UD,
               unsigned short* __restrict__ RX,
               int K, int t0)
{
    __shared__ unsigned short Als[128*32];
    __shared__ unsigned short Bls[128*32];
    const int tid = threadIdx.x;
    const int m_base = blockIdx.y*128;
    const int n_base = blockIdx.x*128;
    const int row0 = tid>>2, row1 = row0+64, quad = tid&3;
    const int wv = tid>>6, lane = tid&63;
    const int wr = (wv>>1)*64, wc = (wv&1)*64;
    const int l15 = lane&15, l4 = lane>>4;

    f32x4 acc[4][4] = {};

    for (int k0 = 0; k0 < K; k0 += 32) {
        const int kq = k0 + quad*8;
        s16x8 a0, a1, b0, b1;
        {
            long r0 = m_base + row0, r1 = m_base + row1;
            const unsigned short *p0, *p1;
            if (AMODE == 1) {
                long g0 = (r0>>5)*512 + t0 + (r0&31);
                long g1 = (r1>>5)*512 + t0 + (r1&31);
                p0 = A1 + g0*1024 + kq; p1 = A1 + g1*1024 + kq;
            } else if (AMODE == 2 && k0 >= 1024) {
                size_t o0 = ((size_t)(r0 & 511)*32 + (r0 >> 9))*1024 + (kq-1024);
                size_t o1 = ((size_t)(r1 & 511)*32 + (r1 >> 9))*1024 + (kq-1024);
                p0 = A2 + o0; p1 = A2 + o1;
            } else {
                p0 = A1 + r0*1024 + kq; p1 = A1 + r1*1024 + kq;
            }
            a0 = *(const s16x8*)p0; a1 = *(const s16x8*)p1;
        }
        b0 = *(const s16x8*)(Bw + (size_t)(n_base+row0)*2048 + kq);
        b1 = *(const s16x8*)(Bw + (size_t)(n_base+row1)*2048 + kq);
        __syncthreads();
        *(s16x8*)&Als[row0*32 + quad*8] = a0;
        *(s16x8*)&Als[row1*32 + quad*8] = a1;
        *(s16x8*)&Bls[row0*32 + quad*8] = b0;
        *(s16x8*)&Bls[row1*32 + quad*8] = b1;
        __syncthreads();
        s16x8 af[4], bfr[4];
#pragma unroll
        for (int i = 0; i < 4; ++i) {
            af[i]  = *(const s16x8*)&Als[(wr + i*16 + l15)*32 + l4*8];
            bfr[i] = *(const s16x8*)&Bls[(wc + i*16 + l15)*32 + l4*8];
        }
#pragma unroll
        for (int mi = 0; mi < 4; ++mi)
#pragma unroll
            for (int ni = 0; ni < 4; ++ni)
                acc[mi][ni] = __builtin_amdgcn_mfma_f32_16x16x32_bf16(
                    af[mi], bfr[ni], acc[mi][ni], 0, 0, 0);
    }

#pragma unroll
    for (int mi = 0; mi < 4; ++mi)
#pragma unroll
    for (int ni = 0; ni < 4; ++ni)
#pragma unroll
    for (int q = 0; q < 4; ++q) {
        int row = m_base + wr + mi*16 + l4*4 + q;
        int col = n_base + wc + ni*16 + l15;
        float v = acc[mi][ni][q] + bias[col];
        if (EMODE == 0) {
            C[(size_t)row*ldc + col] = v;
        } else if (EMODE == 1) {
            float s = sigf(v);
            if (col < 1024) {
                UD[(size_t)row*1024 + col] = s;
            } else {
                int jj = col - 1024;
                RX[(size_t)row*1024 + jj] = f2b(s * X[(size_t)row*1024 + jj]);
            }
        } else {
            float hc = tanhf(v);
            float xv = X[(size_t)row*1024 + col];
            float ud = UD[(size_t)row*1024 + col];
            C[(size_t)row*1024 + col] = xv + ud*(hc - xv);
        }
    }
}

// ---------------------------------------------------------------------------
// Persistent scan: 32 blocks x 512 threads (8 waves), 32 steps/launch,
// 2 flag barriers/step. Recurrent state f32 (hf32 LDS + hi/lo exchange).
// Matmuls: 3-term split-bf16 MFMA (hi*Whi + lo*Whi + hi*Wlo) ~ f32 accurate.
// LDS rows padded to 1032 shorts (bank-conflict-free, no swizzle).
// ---------------------------------------------------------------------------
__global__ __launch_bounds__(512)
void scan_mfma2(const float* __restrict__ chunk,    // [32n*32tl][3072]
                const unsigned short* __restrict__ WT,
                const unsigned short* __restrict__ Wlo,
                const float* __restrict__ prev_ht,
                unsigned short* __restrict__ htR,   // [512][32][1024] hi
                unsigned short* __restrict__ hloR,  // [32][32][1024] lo ring
                unsigned short* __restrict__ rhiR,  // [32][32][1024]
                unsigned short* __restrict__ rloR,  // [32][32][1024]
                float* __restrict__ hper,           // [16][32][64]
                unsigned* __restrict__ flags,
                int t0, int bidx0)
{
    __shared__ unsigned short shi[32*1032];
    __shared__ unsigned short slo[32*1032];
    __shared__ float hf32[2048];
    __shared__ float uls [2048];
    const int tid  = threadIdx.x;
    const int b    = blockIdx.x;
    const bool isU = (b < 16);
    const int w    = tid >> 6;        // 0..7
    const int wcg  = w & 3;           // col group (16 cols)
    const int wn   = w >> 2;          // n half (16 rows)
    const int lane = tid & 63;
    const int l15  = lane & 15;
    const int l4   = lane >> 4;
    const int cb   = b * 64;
    unsigned bidx  = (unsigned)bidx0;

    if (isU) {
        for (int i = tid; i < 2048; i += 512) {
            int n = i >> 6, jl = i & 63;
            hf32[i] = (t0 == 0) ? prev_ht[n*1024 + cb + jl]
                                : hper[((size_t)b*32 + n)*64 + jl];
        }
    }

    for (int tl = 0; tl < CT; ++tl) {
        const int t = t0 + tl;

        // ---- stage h hi/lo --------------------------------------------
        if (t == 0) {
#pragma unroll 2
            for (int it = 0; it < 8; ++it) {
                int g = tid + it*512;          // 0..4095
                int n = g >> 7, kg = (g & 127) * 8;
                f32x4 a = *(const f32x4*)&prev_ht[n*1024 + kg];
                f32x4 c = *(const f32x4*)&prev_ht[n*1024 + kg + 4];
                s16x8 vh, vl;
#pragma unroll
                for (int e = 0; e < 4; ++e) {
                    unsigned short h1 = f2b(a[e]);
                    vh[e]   = (short)h1; vl[e]   = (short)f2b(a[e] - b2f(h1));
                    unsigned short h2 = f2b(c[e]);
                    vh[4+e] = (short)h2; vl[4+e] = (short)f2b(c[e] - b2f(h2));
                }
                *(s16x8*)&shi[n*1032 + kg] = vh;
                *(s16x8*)&slo[n*1032 + kg] = vl;
            }
        } else {
            const unsigned short* shp = htR  + (size_t)(t-1)*32768;
            const unsigned short* slp = hloR + (size_t)((tl-1)&(CT-1))*32768;
#pragma unroll 2
            for (int it = 0; it < 8; ++it) {
                int g = tid + it*512;
                int n = g >> 7, kg = (g & 127) * 8;
                *(s16x8*)&shi[n*1032 + kg] = *(const s16x8*)&shp[n*1024 + kg];
                *(s16x8*)&slo[n*1032 + kg] = *(const s16x8*)&slp[n*1024 + kg];
            }
        }
        __syncthreads();

        // ---- phase A: ur cols [cb, cb+64) -----------------------------
        {
            const int jb = cb + wcg*16;
            f32x4 acc = {0,0,0,0};
            const unsigned short* bph = WT  + (size_t)(jb + l15)*2048 + 1024 + l4*8;
            const unsigned short* bpl = Wlo + (size_t)(jb + l15)*1024 + l4*8;
            const int rbase = wn*16 + l15;
#pragma unroll
            for (int kq = 0; kq < 32; ++kq) {
                int ka = kq*32 + l4*8;
                s16x8 ah = *(const s16x8*)&shi[rbase*1032 + ka];
                s16x8 al = *(const s16x8*)&slo[rbase*1032 + ka];
                s16x8 bh = *(const s16x8*)(bph + kq*32);
                s16x8 bl = *(const s16x8*)(bpl + kq*32);
                acc = __builtin_amdgcn_mfma_f32_16x16x32_bf16(ah, bh, acc, 0,0,0);
                acc = __builtin_amdgcn_mfma_f32_16x16x32_bf16(al, bh, acc, 0,0,0);
                acc = __builtin_amdgcn_mfma_f32_16x16x32_bf16(ah, bl, acc, 0,0,0);
            }
            const int jcol = jb + l15;
#pragma unroll
            for (int q = 0; q < 4; ++q) {
                int n = wn*16 + l4*4 + q;
                float v = acc[q] + chunk[(size_t)((n<<5) + tl)*3072 + jcol];
                float s = sigf(v);
                if (isU) {
                    uls[n*64 + (jcol - cb)] = s;
                } else {
                    int jg = jcol - 1024;
                    float hv = b2f(shi[n*1032 + jg]) + b2f(slo[n*1032 + jg]);
                    float rh = s * hv;
                    unsigned short rhi = f2b(rh);
                    st_sc_b16(&rhiR[((size_t)tl*32 + n)*1024 + jg], rhi);
                    st_sc_b16(&rloR[((size_t)tl*32 + n)*1024 + jg],
                              f2b(rh - b2f(rhi)));
                }
            }
        }
        // ---- barrier 1 ------------------------------------------------
        __syncthreads(); ++bidx;
        if (tid == 0) st_sc_u32(&flags[(unsigned)b*32], bidx);
        if (tid < 32) {
            const unsigned* f = &flags[(unsigned)tid*32];
            while (ld_sc_u32(f) < bidx) __builtin_amdgcn_s_sleep(1);
        }
        __syncthreads();

        if (isU) {
            // ---- stage rh hi/lo --------------------------------------
            const unsigned short* rip = rhiR + (size_t)tl*32768;
            const unsigned short* rlp = rloR + (size_t)tl*32768;
#pragma unroll 2
            for (int it = 0; it < 8; ++it) {
                int g = tid + it*512;
                int n = g >> 7, kg = (g & 127) * 8;
                *(s16x8*)&shi[n*1032 + kg] = *(const s16x8*)&rip[n*1024 + kg];
                *(s16x8*)&slo[n*1032 + kg] = *(const s16x8*)&rlp[n*1024 + kg];
            }
            __syncthreads();
            // ---- phase B: hc cols [cb, cb+64) + h update -------------
            const int jb = cb + wcg*16;
            f32x4 acc = {0,0,0,0};
            const unsigned short* bph = WT  + (size_t)(2048 + jb + l15)*2048 + 1024 + l4*8;
            const unsigned short* bpl = Wlo + (size_t)(2048 + jb + l15)*1024 + l4*8;
            const int rbase = wn*16 + l15;
#pragma unroll
            for (int kq = 0; kq < 32; ++kq) {
                int ka = kq*32 + l4*8;
                s16x8 ah = *(const s16x8*)&shi[rbase*1032 + ka];
                s16x8 al = *(const s16x8*)&slo[rbase*1032 + ka];
                s16x8 bh = *(const s16x8*)(bph + kq*32);
                s16x8 bl = *(const s16x8*)(bpl + kq*32);
                acc = __builtin_amdgcn_mfma_f32_16x16x32_bf16(ah, bh, acc, 0,0,0);
                acc = __builtin_amdgcn_mfma_f32_16x16x32_bf16(al, bh, acc, 0,0,0);
                acc = __builtin_amdgcn_mfma_f32_16x16x32_bf16(ah, bl, acc, 0,0,0);
            }
#pragma unroll
            for (int q = 0; q < 4; ++q) {
                int n  = wn*16 + l4*4 + q;
                int jl = wcg*16 + l15, jg = cb + jl;
                float v = acc[q] + chunk[(size_t)((n<<5) + tl)*3072 + 2048 + jg];
                float hcv  = tanhf(v);
                float hold = hf32[n*64 + jl];
                float uu   = uls [n*64 + jl];
                float hn = hold + uu*(hcv - hold);
                hf32[n*64 + jl] = hn;
                unsigned short hi = f2b(hn);
                st_sc_b16(&htR [((size_t)t*32  + n)*1024 + jg], hi);
                st_sc_b16(&hloR[((size_t)tl*32 + n)*1024 + jg],
                          f2b(hn - b2f(hi)));
                if (tl == CT-1) st_sc1(&hper[((size_t)b*32 + n)*64 + jl], hn);
            }
        }
        // ---- barrier 2 ------------------------------------------------
        __syncthreads(); ++bidx;
        if (tid == 0) st_sc_u32(&flags[(unsigned)b*32], bidx);
        if (tid < 32) {
            const unsigned* f = &flags[(unsigned)tid*32];
            while (ld_sc_u32(f) < bidx) __builtin_amdgcn_s_sleep(1);
        }
        __syncthreads();
    }
}

// ---- last_h: out[n*1024+j] = hper[(j/64)*32 + n][j%64] ---------------------
__global__ __launch_bounds__(256)
void k_lasth(const float* __restrict__ hper, float* __restrict__ dst)
{
    int i = blockIdx.x*256 + threadIdx.x;     // 32768
    int n = i >> 10, j = i & 1023;
    dst[i] = hper[(((size_t)(j >> 6))*32 + n)*64 + (j & 63)];
}

// ---------------------------------------------------------------------------
extern "C" void kernel_launch(void* const* d_in, const int* in_sizes, int n_in,
                              void* d_out, int out_size, void* d_ws, size_t ws_size,
                              hipStream_t stream)
{
    const float* x       = (const float*)d_in[0];
    const float* prev_ht = (const float*)d_in[1];
    const float* weight  = (const float*)d_in[2];
    const float* bias    = (const float*)d_in[3];
    float* out = (float*)d_out;
    float* ws  = (float*)d_ws;

    // ws layout (float units):
    unsigned short* WT   = (unsigned short*)ws;                 // 6,291,456 f
    unsigned short* Wlo  = (unsigned short*)(ws + 6291456);     // 1,572,864 f
    unsigned short* htR  = (unsigned short*)(ws + 7864320);     // 8,388,608 f
    unsigned short* xbf  = (unsigned short*)(ws + 16252928);    // 8,388,608 f
    float* zone          = ws + 24641536;                       // 8,388,608 f
    float* chunk         = zone;                                //  3,145,728 f
    unsigned short* rhiR = (unsigned short*)(zone + 3145728);   //    524,288 f
    unsigned short* rloR = (unsigned short*)(zone + 3670016);   //    524,288 f
    unsigned short* hloR = (unsigned short*)(zone + 4194304);   //    524,288 f
    unsigned short* rxbf = (unsigned short*)zone;               // overlay post-scan
    float* hper          = ws + 33030144;                       //     32,768 f
    unsigned* flags      = (unsigned*)(ws + 33062912);          //      8,192 f
    const size_t needed = (size_t)33071104 * 4;                 // 132.3 MB
    if (ws_size < needed) return;

    hipMemsetAsync(flags, 0, 4096, stream);
    k_wt <<<dim3(96,32), 256, 0, stream>>>(weight, WT);
    k_wlo<<<dim3(48,16), 256, 0, stream>>>(weight, Wlo);
    k_xbf<<<16384, 256, 0, stream>>>(x, xbf);

    for (int seg = 0; seg < 16; ++seg) {
        int t0 = seg * CT;
        int bidx0 = seg * (2*CT);
        // gates chunk: x rows (n*512 + t0 + tl) @ W[:,0:3072] + bt
        gemm_mfma<1,0><<<dim3(24,8), 256, 0, stream>>>(
            xbf, nullptr, WT, chunk, 3072, bias, nullptr, nullptr, nullptr,
            1024, t0);
        const float* gc = chunk;
        const unsigned short* WTc = WT;
        const unsigned short* Wloc = Wlo;
        void* args[] = { (void*)&gc, (void*)&WTc, (void*)&Wloc, (void*)&prev_ht,
                         (void*)&htR, (void*)&hloR, (void*)&rhiR, (void*)&rloR,
                         (void*)&hper, (void*)&flags, (void*)&t0, (void*)&bidx0 };
        hipLaunchCooperativeKernel((void*)scan_mfma2, dim3(32), dim3(512),
                                   args, 0, stream);
    }

    // depth urd: [x|ht] @ W[:,3072:5120] -> sig -> ud (d_out), rx (bf16)
    gemm_mfma<2,1><<<dim3(16,128), 256, 0, stream>>>(
        xbf, htR, WT + (size_t)3072*2048, nullptr, 0, bias + 3072,
        x, out, rxbf, 2048, 0);
    // depth hc: [rx|ht] @ W[:,5120:6144] -> tanh -> final out
    gemm_mfma<2,2><<<dim3(8,128), 256, 0, stream>>>(
        rxbf, htR, WT + (size_t)5120*2048, out, 1024, bias + 5120,
        x, out, nullptr, 2048, 0);

    k_lasth<<<128, 256, 0, stream>>>(hper, out + (size_t)16384*1024);
}